// Round 3
// baseline (1008.666 us; speedup 1.0000x reference)
//
#include <hip/hip_runtime.h>
#include <hip/hip_fp16.h>

#define RES 32
#define R3 32768
#define BATCH 16
#define CCH 64
#define NPTS 65536
#define NPTS4 16384

// ============================ common small kernels ============================

__global__ void statsA_kernel(const float* __restrict__ coords,
                              float* __restrict__ sums) {
    const int bid = blockIdx.x;      // 0..255
    const int b = bid >> 4;
    const int chunk = bid & 15;
    const int tid = threadIdx.x;     // 0..255
    const float* cb = coords + (size_t)b * 3 * NPTS;
    const int base4 = chunk * 1024;

    float sx = 0.f, sy = 0.f, sz = 0.f;
    for (int k = tid; k < 1024; k += 256) {
        float4 x4 = reinterpret_cast<const float4*>(cb)[base4 + k];
        float4 y4 = reinterpret_cast<const float4*>(cb + NPTS)[base4 + k];
        float4 z4 = reinterpret_cast<const float4*>(cb + 2 * NPTS)[base4 + k];
        sx += (x4.x + x4.y) + (x4.z + x4.w);
        sy += (y4.x + y4.y) + (y4.z + y4.w);
        sz += (z4.x + z4.y) + (z4.z + z4.w);
    }
    __shared__ float red[3][256];
    red[0][tid] = sx; red[1][tid] = sy; red[2][tid] = sz;
    __syncthreads();
    for (int s = 128; s > 0; s >>= 1) {
        if (tid < s) {
            red[0][tid] += red[0][tid + s];
            red[1][tid] += red[1][tid + s];
            red[2][tid] += red[2][tid + s];
        }
        __syncthreads();
    }
    if (tid == 0) {
        atomicAdd(&sums[b * 3 + 0], red[0][0]);
        atomicAdd(&sums[b * 3 + 1], red[1][0]);
        atomicAdd(&sums[b * 3 + 2], red[2][0]);
    }
}

__global__ void statsB_kernel(const float* __restrict__ coords,
                              const float* __restrict__ sums,
                              unsigned int* __restrict__ r2bits) {
    const int bid = blockIdx.x;
    const int b = bid >> 4;
    const int chunk = bid & 15;
    const int tid = threadIdx.x;
    const float mx = sums[b * 3 + 0] * (1.0f / NPTS);
    const float my = sums[b * 3 + 1] * (1.0f / NPTS);
    const float mz = sums[b * 3 + 2] * (1.0f / NPTS);
    const float* cb = coords + (size_t)b * 3 * NPTS;
    const int base4 = chunk * 1024;

    float m = 0.f;
    for (int k = tid; k < 1024; k += 256) {
        float4 x4 = reinterpret_cast<const float4*>(cb)[base4 + k];
        float4 y4 = reinterpret_cast<const float4*>(cb + NPTS)[base4 + k];
        float4 z4 = reinterpret_cast<const float4*>(cb + 2 * NPTS)[base4 + k];
        float dx, dy, dz, r2;
        dx = x4.x - mx; dy = y4.x - my; dz = z4.x - mz; r2 = dx*dx + dy*dy + dz*dz; m = fmaxf(m, r2);
        dx = x4.y - mx; dy = y4.y - my; dz = z4.y - mz; r2 = dx*dx + dy*dy + dz*dz; m = fmaxf(m, r2);
        dx = x4.z - mx; dy = y4.z - my; dz = z4.z - mz; r2 = dx*dx + dy*dy + dz*dz; m = fmaxf(m, r2);
        dx = x4.w - mx; dy = y4.w - my; dz = z4.w - mz; r2 = dx*dx + dy*dy + dz*dz; m = fmaxf(m, r2);
    }
    __shared__ float red[256];
    red[tid] = m;
    __syncthreads();
    for (int s = 128; s > 0; s >>= 1) {
        if (tid < s) red[tid] = fmaxf(red[tid], red[tid + s]);
        __syncthreads();
    }
    if (tid == 0)
        atomicMax(&r2bits[b], __float_as_uint(red[0]));
}

__global__ void norm_idx_kernel(const float* __restrict__ coords,
                                const float* __restrict__ sums,
                                const unsigned int* __restrict__ r2bits,
                                float* __restrict__ out_norm,
                                int* __restrict__ idx,
                                unsigned int* __restrict__ counts) {
    const int t = blockIdx.x * blockDim.x + threadIdx.x;
    if (t >= BATCH * NPTS4) return;
    const int b = t >> 14;
    const int n4 = t & (NPTS4 - 1);

    const float mx = sums[b * 3 + 0] * (1.0f / NPTS);
    const float my = sums[b * 3 + 1] * (1.0f / NPTS);
    const float mz = sums[b * 3 + 2] * (1.0f / NPTS);
    const float denom = 2.0f * sqrtf(__uint_as_float(r2bits[b]));

    const float* cb = coords + (size_t)b * 3 * NPTS;
    float4 X = reinterpret_cast<const float4*>(cb)[n4];
    float4 Y = reinterpret_cast<const float4*>(cb + NPTS)[n4];
    float4 Z = reinterpret_cast<const float4*>(cb + 2 * NPTS)[n4];

    float xs[4] = {X.x, X.y, X.z, X.w};
    float ys[4] = {Y.x, Y.y, Y.z, Y.w};
    float zs[4] = {Z.x, Z.y, Z.z, Z.w};
    float xo[4], yo[4], zo[4];
    int fo[4];
    unsigned int* cnt = counts + (size_t)b * R3;
    #pragma unroll
    for (int j = 0; j < 4; ++j) {
        float x = ((xs[j] - mx) / denom + 0.5f) * (float)RES;
        float y = ((ys[j] - my) / denom + 0.5f) * (float)RES;
        float z = ((zs[j] - mz) / denom + 0.5f) * (float)RES;
        x = fminf(fmaxf(x, 0.f), (float)(RES - 1));
        y = fminf(fmaxf(y, 0.f), (float)(RES - 1));
        z = fminf(fmaxf(z, 0.f), (float)(RES - 1));
        xo[j] = x; yo[j] = y; zo[j] = z;
        fo[j] = ((int)rintf(x) * RES + (int)rintf(y)) * RES + (int)rintf(z);
    }
    #pragma unroll
    for (int j = 0; j < 4; ++j) atomicAdd(&cnt[fo[j]], 1u);

    float* ob = out_norm + (size_t)b * 3 * NPTS;
    reinterpret_cast<float4*>(ob)[n4] = make_float4(xo[0], xo[1], xo[2], xo[3]);
    reinterpret_cast<float4*>(ob + NPTS)[n4] = make_float4(yo[0], yo[1], yo[2], yo[3]);
    reinterpret_cast<float4*>(ob + 2 * NPTS)[n4] = make_float4(zo[0], zo[1], zo[2], zo[3]);
    reinterpret_cast<int4*>(idx + (size_t)b * NPTS)[n4] = make_int4(fo[0], fo[1], fo[2], fo[3]);
}

// ===================== sort path: scan, rank, gather-transpose, segsum =====================

// Per-batch exclusive prefix sum of counts[32768] -> start, cursor (copy).
__global__ __launch_bounds__(1024) void scan_kernel(const unsigned int* __restrict__ counts,
                                                    unsigned int* __restrict__ start,
                                                    unsigned int* __restrict__ cursor) {
    const int b = blockIdx.x;
    const unsigned int* cb = counts + (size_t)b * R3;
    unsigned int* sb = start + (size_t)b * R3;
    unsigned int* qb = cursor + (size_t)b * R3;
    const int t = threadIdx.x;

    const uint4* c4 = reinterpret_cast<const uint4*>(cb + t * 32);
    uint4 u[8];
    unsigned int s = 0;
    #pragma unroll
    for (int g = 0; g < 8; ++g) {
        u[g] = c4[g];
        s += u[g].x + u[g].y + u[g].z + u[g].w;
    }
    __shared__ unsigned int red[1024];
    red[t] = s;
    __syncthreads();
    for (int off = 1; off < 1024; off <<= 1) {
        unsigned int v = (t >= off) ? red[t - off] : 0u;
        __syncthreads();
        red[t] += v;
        __syncthreads();
    }
    unsigned int run = (t == 0) ? 0u : red[t - 1];
    #pragma unroll
    for (int g = 0; g < 8; ++g) {
        uint4 st;
        st.x = run; run += u[g].x;
        st.y = run; run += u[g].y;
        st.z = run; run += u[g].z;
        st.w = run; run += u[g].w;
        reinterpret_cast<uint4*>(sb + t * 32)[g] = st;
        reinterpret_cast<uint4*>(qb + t * 32)[g] = st;
    }
}

// rank[n] = position of point n in voxel-sorted order; svox[pos] = voxel id.
__global__ void rank_kernel(const int* __restrict__ idx,
                            unsigned int* __restrict__ cursor,
                            int* __restrict__ rank,
                            unsigned short* __restrict__ svox) {
    const int t = blockIdx.x * blockDim.x + threadIdx.x;
    if (t >= BATCH * NPTS) return;
    const int b = t >> 16;
    const int v = idx[t];
    const unsigned int pos = atomicAdd(&cursor[(size_t)b * R3 + v], 1u);
    rank[t] = (int)pos;
    svox[(size_t)b * NPTS + pos] = (unsigned short)v;
}

// Gather-transpose: ft[b][rank[n]][c] = (half)features[b][c][n].
// Block = (tile of 256 points, batch). 256 threads.
__global__ __launch_bounds__(256) void gt_kernel(const float* __restrict__ features,
                                                 const int* __restrict__ rank,
                                                 __half* __restrict__ ft) {
    __shared__ float tile[64][257];     // pad 257: conflict-free row-write + col-read
    __shared__ int rlds[256];
    const int b = blockIdx.y;
    const int n0 = blockIdx.x * 256;
    const int t = threadIdx.x;
    const int w = t >> 6;
    const int lane = t & 63;

    rlds[t] = rank[(size_t)b * NPTS + n0 + t];

    const float* fb = features + ((size_t)b * CCH) * NPTS + n0;
    for (int c = 0; c < 64; ++c) {
        tile[c][t] = fb[(size_t)c * NPTS + t];   // coalesced 1KB; LDS banks t%32
    }
    __syncthreads();

    __half* fo = ft + ((size_t)b * NPTS) * CCH;
    for (int jg = 0; jg < 64; ++jg) {
        const int j = jg * 4 + w;
        const int row = rlds[j];
        const float val = tile[lane][j];         // banks (lane+j)%32: 2-way, free
        fo[(size_t)row * CCH + lane] = __float2half_rn(val);  // 128B contiguous
    }
}

// Segment-sum: wave owns 32 voxels exclusively; register run-accumulate;
// non-atomic LDS flush; fused divide; coalesced transposed writeout.
__global__ __launch_bounds__(256) void segsum_kernel(const __half* __restrict__ ft,
                                                     const unsigned short* __restrict__ svox,
                                                     const unsigned int* __restrict__ start,
                                                     const unsigned int* __restrict__ counts,
                                                     float* __restrict__ vox) {
    __shared__ float tile[64][129];
    const int b = blockIdx.y;
    const int v0 = blockIdx.x * 128;
    const int t = threadIdx.x;
    const int w = t >> 6;
    const int lane = t & 63;

    for (int i = t; i < 64 * 129; i += 256) ((float*)tile)[i] = 0.f;
    __syncthreads();

    const int vlo = v0 + w * 32;
    const int vhi = vlo + 32;
    const unsigned int js = start[(size_t)b * R3 + vlo];
    const unsigned int je = (vhi < R3) ? start[(size_t)b * R3 + vhi] : NPTS;

    if (js < je) {
        const __half* fb = ft + ((size_t)b * NPTS) * CCH;
        const unsigned short* sv = svox + (size_t)b * NPTS;
        int cur = sv[js];
        float acc = 0.f;
        for (unsigned int j = js; j < je; ++j) {
            const int v = sv[j];                            // wave-uniform
            const float f = __half2float(fb[(size_t)j * CCH + lane]);
            if (v != cur) {                                 // uniform branch
                tile[lane][cur - v0] += acc;                // exclusive: non-atomic
                acc = 0.f;
                cur = v;
            }
            acc += f;
        }
        tile[lane][cur - v0] += acc;
    }
    __syncthreads();

    const unsigned int* cb = counts + (size_t)b * R3 + v0;
    float* ob = vox + ((size_t)b * CCH) * R3 + v0;
    for (int g = 0; g < 32; ++g) {
        const int id = g * 256 + t;       // 0..8191
        const int c = id >> 7;
        const int vv = id & 127;
        const float cnt = (float)cb[vv];
        ob[(size_t)c * R3 + vv] = tile[c][vv] / fmaxf(cnt, 1.f);
    }
}

// ============================ fallback (R1) scatter path ============================

__global__ __launch_bounds__(1024, 1)
void scatter_lds_kernel(const float* __restrict__ features,
                        const int* __restrict__ idx,
                        const unsigned int* __restrict__ counts,
                        float* __restrict__ vox) {
    __shared__ float acc[R3];
    const int bc = blockIdx.x;
    const int b = bc >> 6;

    for (int v = threadIdx.x; v < R3 / 4; v += blockDim.x)
        reinterpret_cast<float4*>(acc)[v] = make_float4(0.f, 0.f, 0.f, 0.f);
    __syncthreads();

    const float4* f4 = reinterpret_cast<const float4*>(features + (size_t)bc * NPTS);
    const int4*   i4 = reinterpret_cast<const int4*>(idx + (size_t)b * NPTS);
    for (int n = threadIdx.x; n < NPTS4; n += blockDim.x) {
        float4 f = f4[n];
        int4   i = i4[n];
        atomicAdd(&acc[i.x], f.x);
        atomicAdd(&acc[i.y], f.y);
        atomicAdd(&acc[i.z], f.z);
        atomicAdd(&acc[i.w], f.w);
    }
    __syncthreads();

    const uint4* c4 = reinterpret_cast<const uint4*>(counts + (size_t)b * R3);
    float4* o4 = reinterpret_cast<float4*>(vox + (size_t)bc * R3);
    for (int v = threadIdx.x; v < R3 / 4; v += blockDim.x) {
        float4 s = reinterpret_cast<float4*>(acc)[v];
        uint4 c = c4[v];
        s.x /= fmaxf((float)c.x, 1.f);
        s.y /= fmaxf((float)c.y, 1.f);
        s.z /= fmaxf((float)c.z, 1.f);
        s.w /= fmaxf((float)c.w, 1.f);
        o4[v] = s;
    }
}

// ============================ launch ============================

extern "C" void kernel_launch(void* const* d_in, const int* in_sizes, int n_in,
                              void* d_out, int out_size, void* d_ws, size_t ws_size,
                              hipStream_t stream) {
    const float* features = (const float*)d_in[0];   // [16,64,65536]
    const float* coords   = (const float*)d_in[1];   // [16,3,65536]

    float* vox      = (float*)d_out;                             // 33,554,432 f32
    float* out_norm = (float*)d_out + (size_t)BATCH * CCH * R3;  // 3,145,728 f32

    char* ws = (char*)d_ws;
    // layout (256B-aligned chunks)
    float*          sums   = (float*)ws;                                   // 192 B
    unsigned int*   r2bits = (unsigned int*)(ws + 192);                    // 64 B
    size_t off = 256;
    int*            idx    = (int*)(ws + off);           off += (size_t)BATCH * NPTS * 4;   // 4 MiB
    unsigned int*   counts = (unsigned int*)(ws + off);  off += (size_t)BATCH * R3 * 4;     // 2 MiB
    unsigned int*   start  = (unsigned int*)(ws + off);  off += (size_t)BATCH * R3 * 4;     // 2 MiB
    unsigned int*   cursor = (unsigned int*)(ws + off);  off += (size_t)BATCH * R3 * 4;     // 2 MiB
    int*            rank   = (int*)(ws + off);           off += (size_t)BATCH * NPTS * 4;   // 4 MiB
    unsigned short* svox   = (unsigned short*)(ws + off); off += (size_t)BATCH * NPTS * 2;  // 2 MiB
    __half*         ft     = (__half*)(ws + off);        off += (size_t)BATCH * NPTS * CCH * 2; // 128 MiB
    const size_t need = off;

    hipMemsetAsync(ws, 0, 256, stream);
    hipMemsetAsync(counts, 0, (size_t)BATCH * R3 * sizeof(unsigned int), stream);

    statsA_kernel<<<256, 256, 0, stream>>>(coords, sums);
    statsB_kernel<<<256, 256, 0, stream>>>(coords, sums, r2bits);
    norm_idx_kernel<<<BATCH * NPTS4 / 256, 256, 0, stream>>>(
        coords, sums, r2bits, out_norm, idx, counts);

    if (ws_size >= need) {
        scan_kernel<<<BATCH, 1024, 0, stream>>>(counts, start, cursor);
        rank_kernel<<<BATCH * NPTS / 256, 256, 0, stream>>>(idx, cursor, rank, svox);
        gt_kernel<<<dim3(NPTS / 256, BATCH), 256, 0, stream>>>(features, rank, ft);
        segsum_kernel<<<dim3(R3 / 128, BATCH), 256, 0, stream>>>(ft, svox, start, counts, vox);
    } else {
        scatter_lds_kernel<<<BATCH * CCH, 1024, 0, stream>>>(features, idx, counts, vox);
    }
}

// Round 6
// 263.575 us; speedup vs baseline: 3.8269x; 3.8269x over previous
//
#include <hip/hip_runtime.h>
#include <hip/hip_fp16.h>

#define RES 32
#define R3 32768
#define BATCH 16
#define CCH 64
#define NPTS 65536
#define NPTS4 16384

// Packed f16 LDS atomic add: ds_pk_add_f16 (non-returning).
// addr_off = 32-bit LDS byte offset (generic LDS ptr truncates to offset on gfx9+).
__device__ __forceinline__ void lds_pk_add_f16(unsigned int addr_off, unsigned int packed) {
    asm volatile("ds_pk_add_f16 %0, %1" :: "v"(addr_off), "v"(packed) : "memory");
}

__device__ __forceinline__ unsigned int pack_rtz(float a, float b) {
    auto p = __builtin_amdgcn_cvt_pkrtz(a, b);   // __fp16 ext_vector(2)
    return __builtin_bit_cast(unsigned int, p);
}

// ---------------- Stats phase A: partial coord sums ----------------
__global__ void statsA_kernel(const float* __restrict__ coords,
                              float* __restrict__ sums) {
    const int bid = blockIdx.x;      // 0..255
    const int b = bid >> 4;
    const int chunk = bid & 15;
    const int tid = threadIdx.x;     // 0..255
    const float* cb = coords + (size_t)b * 3 * NPTS;
    const int base4 = chunk * 1024;

    float sx = 0.f, sy = 0.f, sz = 0.f;
    for (int k = tid; k < 1024; k += 256) {
        float4 x4 = reinterpret_cast<const float4*>(cb)[base4 + k];
        float4 y4 = reinterpret_cast<const float4*>(cb + NPTS)[base4 + k];
        float4 z4 = reinterpret_cast<const float4*>(cb + 2 * NPTS)[base4 + k];
        sx += (x4.x + x4.y) + (x4.z + x4.w);
        sy += (y4.x + y4.y) + (y4.z + y4.w);
        sz += (z4.x + z4.y) + (z4.z + z4.w);
    }
    __shared__ float red[3][256];
    red[0][tid] = sx; red[1][tid] = sy; red[2][tid] = sz;
    __syncthreads();
    for (int s = 128; s > 0; s >>= 1) {
        if (tid < s) {
            red[0][tid] += red[0][tid + s];
            red[1][tid] += red[1][tid + s];
            red[2][tid] += red[2][tid + s];
        }
        __syncthreads();
    }
    if (tid == 0) {
        atomicAdd(&sums[b * 3 + 0], red[0][0]);
        atomicAdd(&sums[b * 3 + 1], red[1][0]);
        atomicAdd(&sums[b * 3 + 2], red[2][0]);
    }
}

// ---------------- Stats phase B: max squared radius ----------------
__global__ void statsB_kernel(const float* __restrict__ coords,
                              const float* __restrict__ sums,
                              unsigned int* __restrict__ r2bits) {
    const int bid = blockIdx.x;
    const int b = bid >> 4;
    const int chunk = bid & 15;
    const int tid = threadIdx.x;
    const float mx = sums[b * 3 + 0] * (1.0f / NPTS);
    const float my = sums[b * 3 + 1] * (1.0f / NPTS);
    const float mz = sums[b * 3 + 2] * (1.0f / NPTS);
    const float* cb = coords + (size_t)b * 3 * NPTS;
    const int base4 = chunk * 1024;

    float m = 0.f;
    for (int k = tid; k < 1024; k += 256) {
        float4 x4 = reinterpret_cast<const float4*>(cb)[base4 + k];
        float4 y4 = reinterpret_cast<const float4*>(cb + NPTS)[base4 + k];
        float4 z4 = reinterpret_cast<const float4*>(cb + 2 * NPTS)[base4 + k];
        float dx, dy, dz, r2;
        dx = x4.x - mx; dy = y4.x - my; dz = z4.x - mz; r2 = dx*dx + dy*dy + dz*dz; m = fmaxf(m, r2);
        dx = x4.y - mx; dy = y4.y - my; dz = z4.y - mz; r2 = dx*dx + dy*dy + dz*dz; m = fmaxf(m, r2);
        dx = x4.z - mx; dy = y4.z - my; dz = z4.z - mz; r2 = dx*dx + dy*dy + dz*dz; m = fmaxf(m, r2);
        dx = x4.w - mx; dy = y4.w - my; dz = z4.w - mz; r2 = dx*dx + dy*dy + dz*dz; m = fmaxf(m, r2);
    }
    __shared__ float red[256];
    red[tid] = m;
    __syncthreads();
    for (int s = 128; s > 0; s >>= 1) {
        if (tid < s) red[tid] = fmaxf(red[tid], red[tid + s]);
        __syncthreads();
    }
    if (tid == 0)
        atomicMax(&r2bits[b], __float_as_uint(red[0]));  // r2 >= 0: bit order = float order
}

// -------- norm coords (output 2), voxel idx, counts --------
__global__ void norm_idx_kernel(const float* __restrict__ coords,
                                const float* __restrict__ sums,
                                const unsigned int* __restrict__ r2bits,
                                float* __restrict__ out_norm,
                                int* __restrict__ idx,
                                unsigned int* __restrict__ counts) {
    const int t = blockIdx.x * blockDim.x + threadIdx.x;
    if (t >= BATCH * NPTS4) return;
    const int b = t >> 14;
    const int n4 = t & (NPTS4 - 1);

    const float mx = sums[b * 3 + 0] * (1.0f / NPTS);
    const float my = sums[b * 3 + 1] * (1.0f / NPTS);
    const float mz = sums[b * 3 + 2] * (1.0f / NPTS);
    const float denom = 2.0f * sqrtf(__uint_as_float(r2bits[b]));

    const float* cb = coords + (size_t)b * 3 * NPTS;
    float4 X = reinterpret_cast<const float4*>(cb)[n4];
    float4 Y = reinterpret_cast<const float4*>(cb + NPTS)[n4];
    float4 Z = reinterpret_cast<const float4*>(cb + 2 * NPTS)[n4];

    float xs[4] = {X.x, X.y, X.z, X.w};
    float ys[4] = {Y.x, Y.y, Y.z, Y.w};
    float zs[4] = {Z.x, Z.y, Z.z, Z.w};
    float xo[4], yo[4], zo[4];
    int fo[4];
    unsigned int* cnt = counts + (size_t)b * R3;
    #pragma unroll
    for (int j = 0; j < 4; ++j) {
        float x = ((xs[j] - mx) / denom + 0.5f) * (float)RES;
        float y = ((ys[j] - my) / denom + 0.5f) * (float)RES;
        float z = ((zs[j] - mz) / denom + 0.5f) * (float)RES;
        x = fminf(fmaxf(x, 0.f), (float)(RES - 1));
        y = fminf(fmaxf(y, 0.f), (float)(RES - 1));
        z = fminf(fmaxf(z, 0.f), (float)(RES - 1));
        xo[j] = x; yo[j] = y; zo[j] = z;
        fo[j] = ((int)rintf(x) * RES + (int)rintf(y)) * RES + (int)rintf(z);
    }
    #pragma unroll
    for (int j = 0; j < 4; ++j) atomicAdd(&cnt[fo[j]], 1u);

    float* ob = out_norm + (size_t)b * 3 * NPTS;
    reinterpret_cast<float4*>(ob)[n4] = make_float4(xo[0], xo[1], xo[2], xo[3]);
    reinterpret_cast<float4*>(ob + NPTS)[n4] = make_float4(yo[0], yo[1], yo[2], yo[3]);
    reinterpret_cast<float4*>(ob + 2 * NPTS)[n4] = make_float4(zo[0], zo[1], zo[2], zo[3]);
    reinterpret_cast<int4*>(idx + (size_t)b * NPTS)[n4] = make_int4(fo[0], fo[1], fo[2], fo[3]);
}

// ---------------- Scatter: LDS packed-f16 atomic accumulation ----------------
// One block per (b, channel-pair). acc[R3] half2 = 128 KiB LDS.
// One ds_pk_add_f16 per point covers BOTH channels -> 33.6M DS lane-atomics total.
__global__ __launch_bounds__(1024, 1)
void scatter2_kernel(const float* __restrict__ features,
                     const int* __restrict__ idx,
                     const unsigned int* __restrict__ counts,
                     float* __restrict__ vox) {
    __shared__ unsigned int acc[R3];             // 32768 x (2 x f16) = 128 KiB
    const int bc2 = blockIdx.x;                  // b*32 + cpair
    const int b  = bc2 >> 5;
    const int c0 = (bc2 & 31) * 2;

    for (int v = threadIdx.x; v < R3 / 4; v += 1024)
        reinterpret_cast<uint4*>(acc)[v] = make_uint4(0u, 0u, 0u, 0u);
    __syncthreads();

    const unsigned int accbase = (unsigned int)(uintptr_t)acc;

    const float4* f0p = reinterpret_cast<const float4*>(
        features + ((size_t)b * CCH + c0) * NPTS);
    const float4* f1p = reinterpret_cast<const float4*>(
        features + ((size_t)b * CCH + c0 + 1) * NPTS);
    const int4* i4p = reinterpret_cast<const int4*>(idx + (size_t)b * NPTS);

    for (int g = threadIdx.x; g < NPTS4; g += 1024) {
        const float4 f0 = f0p[g];
        const float4 f1 = f1p[g];
        const int4 i = i4p[g];
        lds_pk_add_f16(accbase + 4u * (unsigned)i.x, pack_rtz(f0.x, f1.x));
        lds_pk_add_f16(accbase + 4u * (unsigned)i.y, pack_rtz(f0.y, f1.y));
        lds_pk_add_f16(accbase + 4u * (unsigned)i.z, pack_rtz(f0.z, f1.z));
        lds_pk_add_f16(accbase + 4u * (unsigned)i.w, pack_rtz(f0.w, f1.w));
    }
    __syncthreads();

    // writeout: fused divide, two coalesced float4 rows per iteration
    const uint4* c4 = reinterpret_cast<const uint4*>(counts + (size_t)b * R3);
    float* o0 = vox + ((size_t)b * CCH + c0) * R3;
    float* o1 = o0 + R3;
    for (int v = threadIdx.x; v < R3 / 4; v += 1024) {
        const uint4 u = reinterpret_cast<const uint4*>(acc)[v];   // 4 half2
        const uint4 c = c4[v];
        const float2 a0 = __half22float2(__builtin_bit_cast(__half2, u.x));
        const float2 a1 = __half22float2(__builtin_bit_cast(__half2, u.y));
        const float2 a2 = __half22float2(__builtin_bit_cast(__half2, u.z));
        const float2 a3 = __half22float2(__builtin_bit_cast(__half2, u.w));
        const float r0 = 1.f / fmaxf((float)c.x, 1.f);
        const float r1 = 1.f / fmaxf((float)c.y, 1.f);
        const float r2 = 1.f / fmaxf((float)c.z, 1.f);
        const float r3 = 1.f / fmaxf((float)c.w, 1.f);
        reinterpret_cast<float4*>(o0)[v] =
            make_float4(a0.x * r0, a1.x * r1, a2.x * r2, a3.x * r3);
        reinterpret_cast<float4*>(o1)[v] =
            make_float4(a0.y * r0, a1.y * r1, a2.y * r2, a3.y * r3);
    }
}

extern "C" void kernel_launch(void* const* d_in, const int* in_sizes, int n_in,
                              void* d_out, int out_size, void* d_ws, size_t ws_size,
                              hipStream_t stream) {
    const float* features = (const float*)d_in[0];   // [16,64,65536]
    const float* coords   = (const float*)d_in[1];   // [16,3,65536]

    float* vox      = (float*)d_out;                             // 33,554,432 f32
    float* out_norm = (float*)d_out + (size_t)BATCH * CCH * R3;  // 3,145,728 f32

    char* ws = (char*)d_ws;
    float*        sums   = (float*)ws;                       // 192 B
    unsigned int* r2bits = (unsigned int*)(ws + 192);        // 64 B
    int*          idx    = (int*)(ws + 256);                 // 4 MiB
    unsigned int* counts = (unsigned int*)(ws + 256 + (size_t)BATCH * NPTS * 4); // 2 MiB

    (void)hipMemsetAsync(ws, 0, 256, stream);
    (void)hipMemsetAsync(counts, 0, (size_t)BATCH * R3 * sizeof(unsigned int), stream);

    statsA_kernel<<<256, 256, 0, stream>>>(coords, sums);
    statsB_kernel<<<256, 256, 0, stream>>>(coords, sums, r2bits);
    norm_idx_kernel<<<BATCH * NPTS4 / 256, 256, 0, stream>>>(
        coords, sums, r2bits, out_norm, idx, counts);

    scatter2_kernel<<<BATCH * (CCH / 2), 1024, 0, stream>>>(features, idx, counts, vox);
}

// Round 7
// 231.241 us; speedup vs baseline: 4.3620x; 1.1398x over previous
//
#include <hip/hip_runtime.h>
#include <hip/hip_fp16.h>

#define RES 32
#define R3 32768
#define BATCH 16
#define CCH 64
#define NPTS 65536
#define NPTS4 16384

// Packed f16 LDS atomic add: ds_pk_add_f16 (non-returning).
__device__ __forceinline__ void lds_pk_add_f16(unsigned int addr_off, unsigned int packed) {
    asm volatile("ds_pk_add_f16 %0, %1" :: "v"(addr_off), "v"(packed) : "memory");
}

__device__ __forceinline__ unsigned int pack_rtz(float a, float b) {
    auto p = __builtin_amdgcn_cvt_pkrtz(a, b);   // __fp16 ext_vector(2)
    return __builtin_bit_cast(unsigned int, p);
}

// Bank-decorrelating bijective swizzle: flips addr bits 2-4 with a hash of y/x
// bits; keeps low 2 bits (16B-group contiguity) intact.
__device__ __forceinline__ int swz(int i) {
    return i ^ ((((i >> 5) ^ (i >> 10)) & 7) << 2);
}

// ---------------- Stats phase A: partial coord sums ----------------
__global__ void statsA_kernel(const float* __restrict__ coords,
                              float* __restrict__ sums) {
    const int bid = blockIdx.x;      // 0..255
    const int b = bid >> 4;
    const int chunk = bid & 15;
    const int tid = threadIdx.x;     // 0..255
    const float* cb = coords + (size_t)b * 3 * NPTS;
    const int base4 = chunk * 1024;

    float sx = 0.f, sy = 0.f, sz = 0.f;
    for (int k = tid; k < 1024; k += 256) {
        float4 x4 = reinterpret_cast<const float4*>(cb)[base4 + k];
        float4 y4 = reinterpret_cast<const float4*>(cb + NPTS)[base4 + k];
        float4 z4 = reinterpret_cast<const float4*>(cb + 2 * NPTS)[base4 + k];
        sx += (x4.x + x4.y) + (x4.z + x4.w);
        sy += (y4.x + y4.y) + (y4.z + y4.w);
        sz += (z4.x + z4.y) + (z4.z + z4.w);
    }
    __shared__ float red[3][256];
    red[0][tid] = sx; red[1][tid] = sy; red[2][tid] = sz;
    __syncthreads();
    for (int s = 128; s > 0; s >>= 1) {
        if (tid < s) {
            red[0][tid] += red[0][tid + s];
            red[1][tid] += red[1][tid + s];
            red[2][tid] += red[2][tid + s];
        }
        __syncthreads();
    }
    if (tid == 0) {
        atomicAdd(&sums[b * 3 + 0], red[0][0]);
        atomicAdd(&sums[b * 3 + 1], red[1][0]);
        atomicAdd(&sums[b * 3 + 2], red[2][0]);
    }
}

// ---------------- Stats phase B: max squared radius ----------------
__global__ void statsB_kernel(const float* __restrict__ coords,
                              const float* __restrict__ sums,
                              unsigned int* __restrict__ r2bits) {
    const int bid = blockIdx.x;
    const int b = bid >> 4;
    const int chunk = bid & 15;
    const int tid = threadIdx.x;
    const float mx = sums[b * 3 + 0] * (1.0f / NPTS);
    const float my = sums[b * 3 + 1] * (1.0f / NPTS);
    const float mz = sums[b * 3 + 2] * (1.0f / NPTS);
    const float* cb = coords + (size_t)b * 3 * NPTS;
    const int base4 = chunk * 1024;

    float m = 0.f;
    for (int k = tid; k < 1024; k += 256) {
        float4 x4 = reinterpret_cast<const float4*>(cb)[base4 + k];
        float4 y4 = reinterpret_cast<const float4*>(cb + NPTS)[base4 + k];
        float4 z4 = reinterpret_cast<const float4*>(cb + 2 * NPTS)[base4 + k];
        float dx, dy, dz, r2;
        dx = x4.x - mx; dy = y4.x - my; dz = z4.x - mz; r2 = dx*dx + dy*dy + dz*dz; m = fmaxf(m, r2);
        dx = x4.y - mx; dy = y4.y - my; dz = z4.y - mz; r2 = dx*dx + dy*dy + dz*dz; m = fmaxf(m, r2);
        dx = x4.z - mx; dy = y4.z - my; dz = z4.z - mz; r2 = dx*dx + dy*dy + dz*dz; m = fmaxf(m, r2);
        dx = x4.w - mx; dy = y4.w - my; dz = z4.w - mz; r2 = dx*dx + dy*dy + dz*dz; m = fmaxf(m, r2);
    }
    __shared__ float red[256];
    red[tid] = m;
    __syncthreads();
    for (int s = 128; s > 0; s >>= 1) {
        if (tid < s) red[tid] = fmaxf(red[tid], red[tid + s]);
        __syncthreads();
    }
    if (tid == 0)
        atomicMax(&r2bits[b], __float_as_uint(red[0]));  // r2 >= 0: bit order = float order
}

// -------- norm coords (output 2), swizzled voxel idx, LDS-private counts --------
// 128 blocks (8 per batch) x 1024 threads; LDS u32 count array, non-atomic
// partial flush to cnt_part[bid] (no global atomics).
__global__ __launch_bounds__(1024, 1)
void norm_idx_count_kernel(const float* __restrict__ coords,
                           const float* __restrict__ sums,
                           const unsigned int* __restrict__ r2bits,
                           float* __restrict__ out_norm,
                           int* __restrict__ idx_swz,
                           unsigned int* __restrict__ cnt_part) {
    __shared__ unsigned int lcnt[R3];            // 128 KiB
    const int bid = blockIdx.x;                  // 0..127
    const int b = bid >> 3;
    const int chunk = bid & 7;
    const int tid = threadIdx.x;                 // 0..1023

    for (int k = tid; k < R3 / 4; k += 1024)
        reinterpret_cast<uint4*>(lcnt)[k] = make_uint4(0u, 0u, 0u, 0u);
    __syncthreads();

    const float mx = sums[b * 3 + 0] * (1.0f / NPTS);
    const float my = sums[b * 3 + 1] * (1.0f / NPTS);
    const float mz = sums[b * 3 + 2] * (1.0f / NPTS);
    const float denom = 2.0f * sqrtf(__uint_as_float(r2bits[b]));

    const float* cb = coords + (size_t)b * 3 * NPTS;
    float* ob = out_norm + (size_t)b * 3 * NPTS;
    int* ib = idx_swz + (size_t)b * NPTS;

    const int base4 = chunk * 2048;              // 2048 float4-groups per chunk
    #pragma unroll
    for (int it = 0; it < 2; ++it) {
        const int n4 = base4 + it * 1024 + tid;
        float4 X = reinterpret_cast<const float4*>(cb)[n4];
        float4 Y = reinterpret_cast<const float4*>(cb + NPTS)[n4];
        float4 Z = reinterpret_cast<const float4*>(cb + 2 * NPTS)[n4];

        float xs[4] = {X.x, X.y, X.z, X.w};
        float ys[4] = {Y.x, Y.y, Y.z, Y.w};
        float zs[4] = {Z.x, Z.y, Z.z, Z.w};
        float xo[4], yo[4], zo[4];
        int fo[4];
        #pragma unroll
        for (int j = 0; j < 4; ++j) {
            float x = ((xs[j] - mx) / denom + 0.5f) * (float)RES;
            float y = ((ys[j] - my) / denom + 0.5f) * (float)RES;
            float z = ((zs[j] - mz) / denom + 0.5f) * (float)RES;
            x = fminf(fmaxf(x, 0.f), (float)(RES - 1));
            y = fminf(fmaxf(y, 0.f), (float)(RES - 1));
            z = fminf(fmaxf(z, 0.f), (float)(RES - 1));
            xo[j] = x; yo[j] = y; zo[j] = z;
            fo[j] = ((int)rintf(x) * RES + (int)rintf(y)) * RES + (int)rintf(z);
        }
        #pragma unroll
        for (int j = 0; j < 4; ++j) atomicAdd(&lcnt[fo[j]], 1u);

        reinterpret_cast<float4*>(ob)[n4] = make_float4(xo[0], xo[1], xo[2], xo[3]);
        reinterpret_cast<float4*>(ob + NPTS)[n4] = make_float4(yo[0], yo[1], yo[2], yo[3]);
        reinterpret_cast<float4*>(ob + 2 * NPTS)[n4] = make_float4(zo[0], zo[1], zo[2], zo[3]);
        reinterpret_cast<int4*>(ib)[n4] =
            make_int4(swz(fo[0]), swz(fo[1]), swz(fo[2]), swz(fo[3]));
    }
    __syncthreads();

    unsigned int* pb = cnt_part + (size_t)bid * R3;
    for (int k = tid; k < R3 / 4; k += 1024)
        reinterpret_cast<uint4*>(pb)[k] = reinterpret_cast<const uint4*>(lcnt)[k];
}

// ---------------- Reduce 8 count partials per batch -> counts ----------------
__global__ void reduce_counts_kernel(const unsigned int* __restrict__ cnt_part,
                                     unsigned int* __restrict__ counts) {
    const int t = blockIdx.x * 256 + threadIdx.x;   // uint4 index, 16*8192 total
    const int b = t >> 13;
    const int k = t & 8191;
    uint4 s = make_uint4(0u, 0u, 0u, 0u);
    #pragma unroll
    for (int p = 0; p < 8; ++p) {
        uint4 u = reinterpret_cast<const uint4*>(
            cnt_part + (size_t)(b * 8 + p) * R3)[k];
        s.x += u.x; s.y += u.y; s.z += u.z; s.w += u.w;
    }
    reinterpret_cast<uint4*>(counts + (size_t)b * R3)[k] = s;
}

// ---------------- Scatter: LDS packed-f16 atomics, swizzled slots ----------------
__global__ __launch_bounds__(1024, 1)
void scatter2_kernel(const float* __restrict__ features,
                     const int* __restrict__ idx_swz,
                     const unsigned int* __restrict__ counts,
                     float* __restrict__ vox) {
    __shared__ unsigned int acc[R3];             // 32768 x (2 x f16) = 128 KiB
    const int bc2 = blockIdx.x;                  // b*32 + cpair
    const int b  = bc2 >> 5;
    const int c0 = (bc2 & 31) * 2;

    for (int v = threadIdx.x; v < R3 / 4; v += 1024)
        reinterpret_cast<uint4*>(acc)[v] = make_uint4(0u, 0u, 0u, 0u);
    __syncthreads();

    const unsigned int accbase = (unsigned int)(uintptr_t)acc;

    const float4* f0p = reinterpret_cast<const float4*>(
        features + ((size_t)b * CCH + c0) * NPTS);
    const float4* f1p = reinterpret_cast<const float4*>(
        features + ((size_t)b * CCH + c0 + 1) * NPTS);
    const int4* i4p = reinterpret_cast<const int4*>(idx_swz + (size_t)b * NPTS);

    for (int g = threadIdx.x; g < NPTS4; g += 1024) {
        const float4 f0 = f0p[g];
        const float4 f1 = f1p[g];
        const int4 i = i4p[g];                   // pre-swizzled slots
        lds_pk_add_f16(accbase + 4u * (unsigned)i.x, pack_rtz(f0.x, f1.x));
        lds_pk_add_f16(accbase + 4u * (unsigned)i.y, pack_rtz(f0.y, f1.y));
        lds_pk_add_f16(accbase + 4u * (unsigned)i.z, pack_rtz(f0.z, f1.z));
        lds_pk_add_f16(accbase + 4u * (unsigned)i.w, pack_rtz(f0.w, f1.w));
    }
    __syncthreads();

    // writeout: voxel-order iteration, permuted slot read, fused divide
    const uint4* c4 = reinterpret_cast<const uint4*>(counts + (size_t)b * R3);
    float* o0 = vox + ((size_t)b * CCH + c0) * R3;
    float* o1 = o0 + R3;
    for (int k = threadIdx.x; k < R3 / 4; k += 1024) {
        const int ks = k ^ (((k >> 3) ^ (k >> 8)) & 7);   // slot-group of voxel-group k
        const uint4 u = reinterpret_cast<const uint4*>(acc)[ks];
        const uint4 c = c4[k];
        const float2 a0 = __half22float2(__builtin_bit_cast(__half2, u.x));
        const float2 a1 = __half22float2(__builtin_bit_cast(__half2, u.y));
        const float2 a2 = __half22float2(__builtin_bit_cast(__half2, u.z));
        const float2 a3 = __half22float2(__builtin_bit_cast(__half2, u.w));
        const float r0 = 1.f / fmaxf((float)c.x, 1.f);
        const float r1 = 1.f / fmaxf((float)c.y, 1.f);
        const float r2 = 1.f / fmaxf((float)c.z, 1.f);
        const float r3 = 1.f / fmaxf((float)c.w, 1.f);
        reinterpret_cast<float4*>(o0)[k] =
            make_float4(a0.x * r0, a1.x * r1, a2.x * r2, a3.x * r3);
        reinterpret_cast<float4*>(o1)[k] =
            make_float4(a0.y * r0, a1.y * r1, a2.y * r2, a3.y * r3);
    }
}

extern "C" void kernel_launch(void* const* d_in, const int* in_sizes, int n_in,
                              void* d_out, int out_size, void* d_ws, size_t ws_size,
                              hipStream_t stream) {
    const float* features = (const float*)d_in[0];   // [16,64,65536]
    const float* coords   = (const float*)d_in[1];   // [16,3,65536]

    float* vox      = (float*)d_out;                             // 33,554,432 f32
    float* out_norm = (float*)d_out + (size_t)BATCH * CCH * R3;  // 3,145,728 f32

    char* ws = (char*)d_ws;
    float*        sums    = (float*)ws;                      // 192 B
    unsigned int* r2bits  = (unsigned int*)(ws + 192);       // 64 B
    size_t off = 256;
    int*          idx_swz = (int*)(ws + off);           off += (size_t)BATCH * NPTS * 4; // 4 MiB
    unsigned int* counts  = (unsigned int*)(ws + off);  off += (size_t)BATCH * R3 * 4;   // 2 MiB
    unsigned int* cnt_part= (unsigned int*)(ws + off);  off += (size_t)128 * R3 * 4;     // 16 MiB

    (void)hipMemsetAsync(ws, 0, 256, stream);

    statsA_kernel<<<256, 256, 0, stream>>>(coords, sums);
    statsB_kernel<<<256, 256, 0, stream>>>(coords, sums, r2bits);
    norm_idx_count_kernel<<<128, 1024, 0, stream>>>(
        coords, sums, r2bits, out_norm, idx_swz, cnt_part);
    reduce_counts_kernel<<<BATCH * (R3 / 4) / 256, 256, 0, stream>>>(cnt_part, counts);
    scatter2_kernel<<<BATCH * (CCH / 2), 1024, 0, stream>>>(features, idx_swz, counts, vox);
}